// Round 1
// baseline (218.902 us; speedup 1.0000x reference)
//
#include <hip/hip_runtime.h>
#include <hip/hip_bf16.h>
#include <math.h>

#define BB_ 32
#define NM_ 256
#define NO_ 1024
#define DD_ 1024
#define HID_ 2048
#define CC_ 200
#define KK_ 3
#define EPS_ 0.001f
#define ALPHA_ 0.3f

// ---------------- Kernel 1: top-3 nearest scene indices -> counts ----------------
// grid = B*8 blocks, 256 threads. 8 threads per motion token, 32 tokens/block.
__device__ __forceinline__ bool lex_less(float nd, int ni, float d, int i) {
    return (nd < d) || (nd == d && ni < i);
}

__device__ __forceinline__ void ins3(float nd, int ni,
                                     float& d0, int& i0, float& d1, int& i1,
                                     float& d2, int& i2) {
    if (lex_less(nd, ni, d1, i1)) {
        d2 = d1; i2 = i1;
        if (lex_less(nd, ni, d0, i0)) { d1 = d0; i1 = i0; d0 = nd; i0 = ni; }
        else { d1 = nd; i1 = ni; }
    } else if (lex_less(nd, ni, d2, i2)) {
        d2 = nd; i2 = ni;
    }
}

__global__ __launch_bounds__(256) void knn_count_kernel(
        const float* __restrict__ scene_loc, const float* __restrict__ motion_loc,
        int* __restrict__ counts) {
    int bx = blockIdx.x;
    int b = bx >> 3;
    int mc = bx & 7;
    __shared__ float2 sloc[NO_];
    const float2* sl = (const float2*)(scene_loc + (size_t)b * NO_ * 2);
    for (int i = threadIdx.x; i < NO_; i += 256) sloc[i] = sl[i];
    __syncthreads();

    int m = mc * 32 + (threadIdx.x >> 3);
    int lane8 = threadIdx.x & 7;
    float2 ml = ((const float2*)(motion_loc + (size_t)b * NM_ * 2))[m];

    float d0 = INFINITY, d1 = INFINITY, d2 = INFINITY;
    int i0 = NO_, i1 = NO_, i2 = NO_;
    for (int o = lane8; o < NO_; o += 8) {
        float dx = ml.x - sloc[o].x;
        float dy = ml.y - sloc[o].y;
        // match reference per-op rounding (no fma contraction), then sqrt
        float dist = __fsqrt_rn(__fadd_rn(__fmul_rn(dx, dx), __fmul_rn(dy, dy)));
        ins3(dist, o, d0, i0, d1, i1, d2, i2);
    }
    // butterfly merge across the 8-lane group
    for (int mask = 1; mask <= 4; mask <<= 1) {
        float e0 = __shfl_xor(d0, mask); int j0 = __shfl_xor(i0, mask);
        float e1 = __shfl_xor(d1, mask); int j1 = __shfl_xor(i1, mask);
        float e2 = __shfl_xor(d2, mask); int j2 = __shfl_xor(i2, mask);
        ins3(e0, j0, d0, i0, d1, i1, d2, i2);
        ins3(e1, j1, d0, i0, d1, i1, d2, i2);
        ins3(e2, j2, d0, i0, d1, i1, d2, i2);
    }
    if (lane8 == 0) {
        atomicAdd(&counts[b * NO_ + i0], 1);
        atomicAdd(&counts[b * NO_ + i1], 1);
        atomicAdd(&counts[b * NO_ + i2], 1);
    }
}

// ---------------- Kernel 2: x[b,d] partial sums (motion mean + weighted scene) ----
// grid = B*16, 256 threads; segment s handles 80 of the 1280 virtual rows.
__global__ __launch_bounds__(256) void fuse_mean_kernel(
        const float* __restrict__ scene_feat, const float* __restrict__ motion_feat,
        const int* __restrict__ counts, float* __restrict__ xpart) {
    int bx = blockIdx.x;
    int b = bx >> 4;
    int s = bx & 15;
    int t = threadIdx.x;
    const float wmot = 1.0f / (float)NM_;
    const float wsc = ALPHA_ / (float)(NM_ * KK_);

    float4 acc = make_float4(0.f, 0.f, 0.f, 0.f);
    int r0 = s * 80;
    for (int r = r0; r < r0 + 80; ++r) {
        const float4* row;
        float w;
        if (r < NM_) {
            w = wmot;
            row = (const float4*)(motion_feat + ((size_t)b * NM_ + r) * DD_);
        } else {
            int o = r - NM_;
            int cnt = counts[b * NO_ + o];
            if (cnt == 0) continue;
            w = wsc * (float)cnt;
            row = (const float4*)(scene_feat + ((size_t)b * NO_ + o) * DD_);
        }
        float4 v = row[t];
        acc.x = fmaf(w, v.x, acc.x);
        acc.y = fmaf(w, v.y, acc.y);
        acc.z = fmaf(w, v.z, acc.z);
        acc.w = fmaf(w, v.w, acc.w);
    }
    float4* out = (float4*)(xpart + ((size_t)s * BB_ + b) * DD_);
    out[t] = acc;
}

// ---------------- Kernel 3: hpre partials = x @ Wp ------------------------------
// grid = 16 dchunks * 8 jchunks = 128 blocks, 256 threads. acc[32] (all batches).
__global__ __launch_bounds__(256) void fc1_kernel(
        const float* __restrict__ xpart, const float* __restrict__ Wp,
        float* __restrict__ hpart) {
    int jc = blockIdx.x & 7;
    int dc = blockIdx.x >> 3;
    int t = threadIdx.x;
    int j = jc * 256 + t;

    __shared__ float xs[BB_ * 64];
    for (int idx = t; idx < BB_ * 64; idx += 256) {
        int bb = idx >> 6;
        int dl = idx & 63;
        float sum = 0.f;
        #pragma unroll
        for (int s = 0; s < 16; ++s)
            sum += xpart[((size_t)s * BB_ + bb) * DD_ + dc * 64 + dl];
        xs[idx] = sum;
    }
    __syncthreads();

    float acc[BB_];
    #pragma unroll
    for (int bb = 0; bb < BB_; ++bb) acc[bb] = 0.f;

    int d0 = dc * 64;
    for (int dl = 0; dl < 64; ++dl) {
        float w = Wp[(size_t)(d0 + dl) * HID_ + j];
        #pragma unroll
        for (int bb = 0; bb < BB_; ++bb)
            acc[bb] = fmaf(xs[bb * 64 + dl], w, acc[bb]);
    }
    #pragma unroll
    for (int bb = 0; bb < BB_; ++bb)
        hpart[((size_t)dc * BB_ + bb) * HID_ + j] = acc[bb];
}

// ---------------- Kernel 4: h = gelu(hpre+bp); logit = h @ Wc + bc ----------------
// grid = B, 256 threads.
__global__ __launch_bounds__(256) void fc2_kernel(
        const float* __restrict__ hpart, const float* __restrict__ bp,
        const float* __restrict__ Wc, const float* __restrict__ bc,
        float* __restrict__ logits) {
    int b = blockIdx.x;
    int t = threadIdx.x;
    __shared__ float hs[HID_];
    for (int j = t; j < HID_; j += 256) {
        float sum = bp[j];
        #pragma unroll
        for (int dcc = 0; dcc < 16; ++dcc)
            sum += hpart[((size_t)dcc * BB_ + b) * HID_ + j];
        // exact GELU
        hs[j] = 0.5f * sum * (1.0f + erff(sum * 0.70710678118654752f));
    }
    __syncthreads();
    if (t < CC_) {
        float acc = bc[t];
        #pragma unroll 8
        for (int k = 0; k < HID_; ++k)
            acc = fmaf(hs[k], Wc[(size_t)k * CC_ + t], acc);
        logits[(size_t)b * CC_ + t] = acc;
    }
}

// ---------------- Kernel 5: label-smoothed cross entropy --------------------------
// 1 block, 256 threads; 8 lanes per batch row.
__global__ __launch_bounds__(256) void loss_kernel(
        const float* __restrict__ logits, const int* __restrict__ label,
        float* __restrict__ loss_out) {
    int t = threadIdx.x;
    int b = t >> 3;
    int lane = t & 7;
    __shared__ float lossb[BB_];

    float v[25];
    float m = -INFINITY, ssum = 0.f;
    #pragma unroll
    for (int i = 0; i < 25; ++i) {
        float x = logits[(size_t)b * CC_ + lane + i * 8];
        v[i] = x;
        m = fmaxf(m, x);
        ssum += x;
    }
    for (int mask = 1; mask < 8; mask <<= 1) m = fmaxf(m, __shfl_xor(m, mask));
    for (int mask = 1; mask < 8; mask <<= 1) ssum += __shfl_xor(ssum, mask);
    float e = 0.f;
    #pragma unroll
    for (int i = 0; i < 25; ++i) e += expf(v[i] - m);
    for (int mask = 1; mask < 8; mask <<= 1) e += __shfl_xor(e, mask);
    float logZ = m + logf(e);

    if (lane == 0) {
        float nll = logZ - logits[(size_t)b * CC_ + label[b]];
        float smooth = logZ - ssum * (1.0f / (float)CC_);
        lossb[b] = (1.0f - EPS_) * nll + EPS_ * smooth;
    }
    __syncthreads();
    if (t == 0) {
        float s = 0.f;
        for (int i = 0; i < BB_; ++i) s += lossb[i];
        loss_out[0] = s * (1.0f / (float)BB_);
    }
}

extern "C" void kernel_launch(void* const* d_in, const int* in_sizes, int n_in,
                              void* d_out, int out_size, void* d_ws, size_t ws_size,
                              hipStream_t stream) {
    const float* scene_feat  = (const float*)d_in[0];
    const float* motion_feat = (const float*)d_in[1];
    const float* scene_loc   = (const float*)d_in[2];
    const float* motion_loc  = (const float*)d_in[3];
    const int*   label       = (const int*)d_in[4];
    const float* Wp          = (const float*)d_in[5];
    const float* bp          = (const float*)d_in[6];
    const float* Wc          = (const float*)d_in[7];
    const float* bc          = (const float*)d_in[8];
    float* out = (float*)d_out;

    char* ws = (char*)d_ws;
    int* counts  = (int*)ws;                                   // 128 KB
    float* xpart = (float*)(ws + (128 << 10));                 // 2 MB
    float* hpart = (float*)(ws + (128 << 10) + (2 << 20));     // 4 MB

    hipMemsetAsync(counts, 0, BB_ * NO_ * sizeof(int), stream);
    knn_count_kernel<<<BB_ * 8, 256, 0, stream>>>(scene_loc, motion_loc, counts);
    fuse_mean_kernel<<<BB_ * 16, 256, 0, stream>>>(scene_feat, motion_feat, counts, xpart);
    fc1_kernel<<<128, 256, 0, stream>>>(xpart, Wp, hpart);
    fc2_kernel<<<BB_, 256, 0, stream>>>(hpart, bp, Wc, bc, out);
    loss_kernel<<<1, 256, 0, stream>>>(out, label, out + BB_ * CC_);
}

// Round 2
// 145.309 us; speedup vs baseline: 1.5065x; 1.5065x over previous
//
#include <hip/hip_runtime.h>
#include <hip/hip_bf16.h>
#include <math.h>

#define BB_ 32
#define NM_ 256
#define NO_ 1024
#define DD_ 1024
#define HID_ 2048
#define CC_ 200
#define KK_ 3
#define EPS_ 0.001f
#define ALPHA_ 0.3f

// ---------------- Kernel 1: top-3 nearest scene indices -> counts ----------------
// grid = B*8 blocks, 256 threads. 8 threads per motion token, 32 tokens/block.
__device__ __forceinline__ bool lex_less(float nd, int ni, float d, int i) {
    return (nd < d) || (nd == d && ni < i);
}

__device__ __forceinline__ void ins3(float nd, int ni,
                                     float& d0, int& i0, float& d1, int& i1,
                                     float& d2, int& i2) {
    if (lex_less(nd, ni, d1, i1)) {
        d2 = d1; i2 = i1;
        if (lex_less(nd, ni, d0, i0)) { d1 = d0; i1 = i0; d0 = nd; i0 = ni; }
        else { d1 = nd; i1 = ni; }
    } else if (lex_less(nd, ni, d2, i2)) {
        d2 = nd; i2 = ni;
    }
}

__global__ __launch_bounds__(256) void knn_count_kernel(
        const float* __restrict__ scene_loc, const float* __restrict__ motion_loc,
        int* __restrict__ counts) {
    int bx = blockIdx.x;
    int b = bx >> 3;
    int mc = bx & 7;
    __shared__ float2 sloc[NO_];
    const float2* sl = (const float2*)(scene_loc + (size_t)b * NO_ * 2);
    for (int i = threadIdx.x; i < NO_; i += 256) sloc[i] = sl[i];
    __syncthreads();

    int m = mc * 32 + (threadIdx.x >> 3);
    int lane8 = threadIdx.x & 7;
    float2 ml = ((const float2*)(motion_loc + (size_t)b * NM_ * 2))[m];

    float d0 = INFINITY, d1 = INFINITY, d2 = INFINITY;
    int i0 = NO_, i1 = NO_, i2 = NO_;
    for (int o = lane8; o < NO_; o += 8) {
        float dx = ml.x - sloc[o].x;
        float dy = ml.y - sloc[o].y;
        // match reference per-op rounding (no fma contraction), then sqrt
        float dist = __fsqrt_rn(__fadd_rn(__fmul_rn(dx, dx), __fmul_rn(dy, dy)));
        ins3(dist, o, d0, i0, d1, i1, d2, i2);
    }
    // butterfly merge across the 8-lane group
    for (int mask = 1; mask <= 4; mask <<= 1) {
        float e0 = __shfl_xor(d0, mask); int j0 = __shfl_xor(i0, mask);
        float e1 = __shfl_xor(d1, mask); int j1 = __shfl_xor(i1, mask);
        float e2 = __shfl_xor(d2, mask); int j2 = __shfl_xor(i2, mask);
        ins3(e0, j0, d0, i0, d1, i1, d2, i2);
        ins3(e1, j1, d0, i0, d1, i1, d2, i2);
        ins3(e2, j2, d0, i0, d1, i1, d2, i2);
    }
    if (lane8 == 0) {
        atomicAdd(&counts[b * NO_ + i0], 1);
        atomicAdd(&counts[b * NO_ + i1], 1);
        atomicAdd(&counts[b * NO_ + i2], 1);
    }
}

// ---------------- Kernel 2: x[b,d] partial sums (motion mean + weighted scene) ----
// grid = B*16, 256 threads; segment s handles 80 of the 1280 virtual rows.
__global__ __launch_bounds__(256) void fuse_mean_kernel(
        const float* __restrict__ scene_feat, const float* __restrict__ motion_feat,
        const int* __restrict__ counts, float* __restrict__ xpart) {
    int bx = blockIdx.x;
    int b = bx >> 4;
    int s = bx & 15;
    int t = threadIdx.x;
    const float wmot = 1.0f / (float)NM_;
    const float wsc = ALPHA_ / (float)(NM_ * KK_);

    float4 acc = make_float4(0.f, 0.f, 0.f, 0.f);
    int r0 = s * 80;
    for (int r = r0; r < r0 + 80; ++r) {
        const float4* row;
        float w;
        if (r < NM_) {
            w = wmot;
            row = (const float4*)(motion_feat + ((size_t)b * NM_ + r) * DD_);
        } else {
            int o = r - NM_;
            int cnt = counts[b * NO_ + o];
            if (cnt == 0) continue;
            w = wsc * (float)cnt;
            row = (const float4*)(scene_feat + ((size_t)b * NO_ + o) * DD_);
        }
        float4 v = row[t];
        acc.x = fmaf(w, v.x, acc.x);
        acc.y = fmaf(w, v.y, acc.y);
        acc.z = fmaf(w, v.z, acc.z);
        acc.w = fmaf(w, v.w, acc.w);
    }
    float4* out = (float4*)(xpart + ((size_t)s * BB_ + b) * DD_);
    out[t] = acc;
}

// ---------------- Kernel 3: hpre partials = x @ Wp ------------------------------
// grid = 16 dchunks * 8 jchunks = 128 blocks, 256 threads. acc[32] (all batches).
__global__ __launch_bounds__(256) void fc1_kernel(
        const float* __restrict__ xpart, const float* __restrict__ Wp,
        float* __restrict__ hpart) {
    int jc = blockIdx.x & 7;
    int dc = blockIdx.x >> 3;
    int t = threadIdx.x;
    int j = jc * 256 + t;

    __shared__ float xs[BB_ * 64];
    for (int idx = t; idx < BB_ * 64; idx += 256) {
        int bb = idx >> 6;
        int dl = idx & 63;
        float sum = 0.f;
        #pragma unroll
        for (int s = 0; s < 16; ++s)
            sum += xpart[((size_t)s * BB_ + bb) * DD_ + dc * 64 + dl];
        xs[idx] = sum;
    }
    __syncthreads();

    float acc[BB_];
    #pragma unroll
    for (int bb = 0; bb < BB_; ++bb) acc[bb] = 0.f;

    int d0 = dc * 64;
    for (int dl = 0; dl < 64; ++dl) {
        float w = Wp[(size_t)(d0 + dl) * HID_ + j];
        #pragma unroll
        for (int bb = 0; bb < BB_; ++bb)
            acc[bb] = fmaf(xs[bb * 64 + dl], w, acc[bb]);
    }
    #pragma unroll
    for (int bb = 0; bb < BB_; ++bb)
        hpart[((size_t)dc * BB_ + bb) * HID_ + j] = acc[bb];
}

// ---------------- Kernel 4: lpart[kc][b][c] = sum_{k in chunk} gelu(h)[b,k]*Wc[k,c]
// grid = 8 kchunks * 32 b = 256 blocks, 256 threads.
// Phase 1: each thread finalizes one h element (reduce 16 partials + bp, exact GELU).
// Phase 2: 200 threads, coalesced Wc loads, smem-broadcast h, 256-step k loop.
__global__ __launch_bounds__(256) void fc2_partial_kernel(
        const float* __restrict__ hpart, const float* __restrict__ bp,
        const float* __restrict__ Wc, float* __restrict__ lpart) {
    int bx = blockIdx.x;
    int b = bx & 31;
    int kc = bx >> 5;
    int t = threadIdx.x;
    __shared__ float hs[256];

    int k = kc * 256 + t;
    float sum = bp[k];
    #pragma unroll
    for (int dcc = 0; dcc < 16; ++dcc)
        sum += hpart[((size_t)dcc * BB_ + b) * HID_ + k];
    // exact GELU
    hs[t] = 0.5f * sum * (1.0f + erff(sum * 0.70710678118654752f));
    __syncthreads();

    if (t < CC_) {
        float acc0 = 0.f, acc1 = 0.f;
        const float* wc = Wc + (size_t)kc * 256 * CC_ + t;
        #pragma unroll 8
        for (int k2 = 0; k2 < 256; k2 += 2) {
            acc0 = fmaf(hs[k2],     wc[(size_t)k2 * CC_],       acc0);
            acc1 = fmaf(hs[k2 + 1], wc[(size_t)(k2 + 1) * CC_], acc1);
        }
        lpart[((size_t)kc * BB_ + b) * CC_ + t] = acc0 + acc1;
    }
}

// ---------------- Kernel 5: logits = sum_kc lpart + bc ---------------------------
// grid = B, 256 threads (200 active).
__global__ __launch_bounds__(256) void logits_kernel(
        const float* __restrict__ lpart, const float* __restrict__ bc,
        float* __restrict__ logits) {
    int b = blockIdx.x;
    int t = threadIdx.x;
    if (t < CC_) {
        float acc = bc[t];
        #pragma unroll
        for (int kc = 0; kc < 8; ++kc)
            acc += lpart[((size_t)kc * BB_ + b) * CC_ + t];
        logits[(size_t)b * CC_ + t] = acc;
    }
}

// ---------------- Kernel 6: label-smoothed cross entropy --------------------------
// 1 block, 256 threads; 8 lanes per batch row.
__global__ __launch_bounds__(256) void loss_kernel(
        const float* __restrict__ logits, const int* __restrict__ label,
        float* __restrict__ loss_out) {
    int t = threadIdx.x;
    int b = t >> 3;
    int lane = t & 7;
    __shared__ float lossb[BB_];

    float v[25];
    float m = -INFINITY, ssum = 0.f;
    #pragma unroll
    for (int i = 0; i < 25; ++i) {
        float x = logits[(size_t)b * CC_ + lane + i * 8];
        v[i] = x;
        m = fmaxf(m, x);
        ssum += x;
    }
    for (int mask = 1; mask < 8; mask <<= 1) m = fmaxf(m, __shfl_xor(m, mask));
    for (int mask = 1; mask < 8; mask <<= 1) ssum += __shfl_xor(ssum, mask);
    float e = 0.f;
    #pragma unroll
    for (int i = 0; i < 25; ++i) e += expf(v[i] - m);
    for (int mask = 1; mask < 8; mask <<= 1) e += __shfl_xor(e, mask);
    float logZ = m + logf(e);

    if (lane == 0) {
        float nll = logZ - logits[(size_t)b * CC_ + label[b]];
        float smooth = logZ - ssum * (1.0f / (float)CC_);
        lossb[b] = (1.0f - EPS_) * nll + EPS_ * smooth;
    }
    __syncthreads();
    if (t == 0) {
        float s = 0.f;
        for (int i = 0; i < BB_; ++i) s += lossb[i];
        loss_out[0] = s * (1.0f / (float)BB_);
    }
}

extern "C" void kernel_launch(void* const* d_in, const int* in_sizes, int n_in,
                              void* d_out, int out_size, void* d_ws, size_t ws_size,
                              hipStream_t stream) {
    const float* scene_feat  = (const float*)d_in[0];
    const float* motion_feat = (const float*)d_in[1];
    const float* scene_loc   = (const float*)d_in[2];
    const float* motion_loc  = (const float*)d_in[3];
    const int*   label       = (const int*)d_in[4];
    const float* Wp          = (const float*)d_in[5];
    const float* bp          = (const float*)d_in[6];
    const float* Wc          = (const float*)d_in[7];
    const float* bc          = (const float*)d_in[8];
    float* out = (float*)d_out;

    char* ws = (char*)d_ws;
    int* counts  = (int*)ws;                                           // 128 KB
    float* xpart = (float*)(ws + (128 << 10));                         // 2 MB
    float* hpart = (float*)(ws + (128 << 10) + (2 << 20));             // 4 MB
    float* lpart = (float*)(ws + (128 << 10) + (6 << 20));             // 0.2 MB

    hipMemsetAsync(counts, 0, BB_ * NO_ * sizeof(int), stream);
    knn_count_kernel<<<BB_ * 8, 256, 0, stream>>>(scene_loc, motion_loc, counts);
    fuse_mean_kernel<<<BB_ * 16, 256, 0, stream>>>(scene_feat, motion_feat, counts, xpart);
    fc1_kernel<<<128, 256, 0, stream>>>(xpart, Wp, hpart);
    fc2_partial_kernel<<<256, 256, 0, stream>>>(hpart, bp, Wc, lpart);
    logits_kernel<<<BB_, 256, 0, stream>>>(lpart, bc, out);
    loss_kernel<<<1, 256, 0, stream>>>(out, label, out + BB_ * CC_);
}

// Round 3
// 131.965 us; speedup vs baseline: 1.6588x; 1.1011x over previous
//
#include <hip/hip_runtime.h>
#include <hip/hip_bf16.h>
#include <math.h>

#define BB_ 32
#define NM_ 256
#define NO_ 1024
#define DD_ 1024
#define HID_ 2048
#define CC_ 200
#define KK_ 3
#define EPS_ 0.001f
#define ALPHA_ 0.3f

// ---------------- Kernel 1: top-3 nearest scene indices per motion token ---------
// grid = B*8 blocks, 256 threads. 8 threads per motion token, 32 tokens/block.
// Writes idx_buf[b][m][3] with plain stores (no init, no atomics needed).
__device__ __forceinline__ bool lex_less(float nd, int ni, float d, int i) {
    return (nd < d) || (nd == d && ni < i);
}

__device__ __forceinline__ void ins3(float nd, int ni,
                                     float& d0, int& i0, float& d1, int& i1,
                                     float& d2, int& i2) {
    if (lex_less(nd, ni, d1, i1)) {
        d2 = d1; i2 = i1;
        if (lex_less(nd, ni, d0, i0)) { d1 = d0; i1 = i0; d0 = nd; i0 = ni; }
        else { d1 = nd; i1 = ni; }
    } else if (lex_less(nd, ni, d2, i2)) {
        d2 = nd; i2 = ni;
    }
}

__global__ __launch_bounds__(256) void knn_idx_kernel(
        const float* __restrict__ scene_loc, const float* __restrict__ motion_loc,
        int* __restrict__ idx_buf) {
    int bx = blockIdx.x;
    int b = bx >> 3;
    int mc = bx & 7;
    __shared__ float2 sloc[NO_];
    const float2* sl = (const float2*)(scene_loc + (size_t)b * NO_ * 2);
    for (int i = threadIdx.x; i < NO_; i += 256) sloc[i] = sl[i];
    __syncthreads();

    int m = mc * 32 + (threadIdx.x >> 3);
    int lane8 = threadIdx.x & 7;
    float2 ml = ((const float2*)(motion_loc + (size_t)b * NM_ * 2))[m];

    float d0 = INFINITY, d1 = INFINITY, d2 = INFINITY;
    int i0 = NO_, i1 = NO_, i2 = NO_;
    for (int o = lane8; o < NO_; o += 8) {
        float dx = ml.x - sloc[o].x;
        float dy = ml.y - sloc[o].y;
        // match reference per-op rounding (no fma contraction), then sqrt
        float dist = __fsqrt_rn(__fadd_rn(__fmul_rn(dx, dx), __fmul_rn(dy, dy)));
        ins3(dist, o, d0, i0, d1, i1, d2, i2);
    }
    // butterfly merge across the 8-lane group
    for (int mask = 1; mask <= 4; mask <<= 1) {
        float e0 = __shfl_xor(d0, mask); int j0 = __shfl_xor(i0, mask);
        float e1 = __shfl_xor(d1, mask); int j1 = __shfl_xor(i1, mask);
        float e2 = __shfl_xor(d2, mask); int j2 = __shfl_xor(i2, mask);
        ins3(e0, j0, d0, i0, d1, i1, d2, i2);
        ins3(e1, j1, d0, i0, d1, i1, d2, i2);
        ins3(e2, j2, d0, i0, d1, i1, d2, i2);
    }
    if (lane8 == 0) {
        int base = (b * NM_ + m) * 3;
        idx_buf[base]     = i0;
        idx_buf[base + 1] = i1;
        idx_buf[base + 2] = i2;
    }
}

// ---------------- Kernel 2: x[b,d] partial sums (motion mean + weighted scene) ----
// grid = B*16, 256 threads; segment s handles 80 of the 1280 virtual rows.
// Builds per-b scene counts in LDS from idx_buf (768 entries), then weighted sum.
__global__ __launch_bounds__(256) void fuse_mean_kernel(
        const float* __restrict__ scene_feat, const float* __restrict__ motion_feat,
        const int* __restrict__ idx_buf, float* __restrict__ xpart) {
    int bx = blockIdx.x;
    int b = bx >> 4;
    int s = bx & 15;
    int t = threadIdx.x;
    const float wmot = 1.0f / (float)NM_;
    const float wsc = ALPHA_ / (float)(NM_ * KK_);

    __shared__ int cnt[NO_];
    for (int i = t; i < NO_; i += 256) cnt[i] = 0;
    __syncthreads();
    for (int i = t; i < NM_ * KK_; i += 256)
        atomicAdd(&cnt[idx_buf[b * NM_ * KK_ + i]], 1);
    __syncthreads();

    float4 acc = make_float4(0.f, 0.f, 0.f, 0.f);
    int r0 = s * 80;
    for (int r = r0; r < r0 + 80; ++r) {
        const float4* row;
        float w;
        if (r < NM_) {
            w = wmot;
            row = (const float4*)(motion_feat + ((size_t)b * NM_ + r) * DD_);
        } else {
            int o = r - NM_;
            int c = cnt[o];
            if (c == 0) continue;
            w = wsc * (float)c;
            row = (const float4*)(scene_feat + ((size_t)b * NO_ + o) * DD_);
        }
        float4 v = row[t];
        acc.x = fmaf(w, v.x, acc.x);
        acc.y = fmaf(w, v.y, acc.y);
        acc.z = fmaf(w, v.z, acc.z);
        acc.w = fmaf(w, v.w, acc.w);
    }
    float4* out = (float4*)(xpart + ((size_t)s * BB_ + b) * DD_);
    out[t] = acc;
}

// ---------------- Kernel 3: hpre partials = x @ Wp ------------------------------
// grid = 32 dchunks * 8 jchunks = 256 blocks, 256 threads. acc[32] (all batches).
__global__ __launch_bounds__(256) void fc1_kernel(
        const float* __restrict__ xpart, const float* __restrict__ Wp,
        float* __restrict__ hpart) {
    int jc = blockIdx.x & 7;
    int dc = blockIdx.x >> 3;
    int t = threadIdx.x;
    int j = jc * 256 + t;

    __shared__ float xs[BB_ * 32];
    for (int idx = t; idx < BB_ * 32; idx += 256) {
        int bb = idx >> 5;
        int dl = idx & 31;
        float sum = 0.f;
        #pragma unroll
        for (int s = 0; s < 16; ++s)
            sum += xpart[((size_t)s * BB_ + bb) * DD_ + dc * 32 + dl];
        xs[idx] = sum;
    }
    __syncthreads();

    float acc[BB_];
    #pragma unroll
    for (int bb = 0; bb < BB_; ++bb) acc[bb] = 0.f;

    int d0 = dc * 32;
    for (int dl = 0; dl < 32; ++dl) {
        float w = Wp[(size_t)(d0 + dl) * HID_ + j];
        #pragma unroll
        for (int bb = 0; bb < BB_; ++bb)
            acc[bb] = fmaf(xs[bb * 32 + dl], w, acc[bb]);
    }
    #pragma unroll
    for (int bb = 0; bb < BB_; ++bb)
        hpart[((size_t)dc * BB_ + bb) * HID_ + j] = acc[bb];
}

// ---------------- Kernel 4: lpart[kc][b][c] = sum_{k in chunk} gelu(h)[b,k]*Wc[k,c]
// grid = 8 kchunks * 32 b = 256 blocks, 256 threads.
__global__ __launch_bounds__(256) void fc2_partial_kernel(
        const float* __restrict__ hpart, const float* __restrict__ bp,
        const float* __restrict__ Wc, float* __restrict__ lpart) {
    int bx = blockIdx.x;
    int b = bx & 31;
    int kc = bx >> 5;
    int t = threadIdx.x;
    __shared__ float hs[256];

    int k = kc * 256 + t;
    float sum = bp[k];
    #pragma unroll
    for (int dcc = 0; dcc < 32; ++dcc)
        sum += hpart[((size_t)dcc * BB_ + b) * HID_ + k];
    // exact GELU
    hs[t] = 0.5f * sum * (1.0f + erff(sum * 0.70710678118654752f));
    __syncthreads();

    if (t < CC_) {
        float acc0 = 0.f, acc1 = 0.f;
        const float* wc = Wc + (size_t)kc * 256 * CC_ + t;
        #pragma unroll 8
        for (int k2 = 0; k2 < 256; k2 += 2) {
            acc0 = fmaf(hs[k2],     wc[(size_t)k2 * CC_],       acc0);
            acc1 = fmaf(hs[k2 + 1], wc[(size_t)(k2 + 1) * CC_], acc1);
        }
        lpart[((size_t)kc * BB_ + b) * CC_ + t] = acc0 + acc1;
    }
}

// ---------------- Kernel 5: logits = sum_kc lpart + bc; then smoothed CE loss -----
// 1 block, 256 threads.
__global__ __launch_bounds__(256) void logits_loss_kernel(
        const float* __restrict__ lpart, const float* __restrict__ bc,
        const int* __restrict__ label, float* __restrict__ out) {
    int t = threadIdx.x;
    __shared__ float slog[BB_ * CC_];
    __shared__ float lossb[BB_];

    for (int idx = t; idx < BB_ * CC_; idx += 256) {
        int b = idx / CC_;
        int c = idx - b * CC_;
        float acc = bc[c];
        #pragma unroll
        for (int kc = 0; kc < 8; ++kc)
            acc += lpart[((size_t)kc * BB_ + b) * CC_ + c];
        slog[idx] = acc;
        out[idx] = acc;
    }
    __syncthreads();

    int b = t >> 3;
    int lane = t & 7;
    float v[25];
    float m = -INFINITY, ssum = 0.f;
    #pragma unroll
    for (int i = 0; i < 25; ++i) {
        float x = slog[b * CC_ + lane + i * 8];
        v[i] = x;
        m = fmaxf(m, x);
        ssum += x;
    }
    for (int mask = 1; mask < 8; mask <<= 1) m = fmaxf(m, __shfl_xor(m, mask));
    for (int mask = 1; mask < 8; mask <<= 1) ssum += __shfl_xor(ssum, mask);
    float e = 0.f;
    #pragma unroll
    for (int i = 0; i < 25; ++i) e += expf(v[i] - m);
    for (int mask = 1; mask < 8; mask <<= 1) e += __shfl_xor(e, mask);
    float logZ = m + logf(e);

    if (lane == 0) {
        float nll = logZ - slog[b * CC_ + label[b]];
        float smooth = logZ - ssum * (1.0f / (float)CC_);
        lossb[b] = (1.0f - EPS_) * nll + EPS_ * smooth;
    }
    __syncthreads();
    if (t == 0) {
        float s = 0.f;
        for (int i = 0; i < BB_; ++i) s += lossb[i];
        out[BB_ * CC_] = s * (1.0f / (float)BB_);
    }
}

extern "C" void kernel_launch(void* const* d_in, const int* in_sizes, int n_in,
                              void* d_out, int out_size, void* d_ws, size_t ws_size,
                              hipStream_t stream) {
    const float* scene_feat  = (const float*)d_in[0];
    const float* motion_feat = (const float*)d_in[1];
    const float* scene_loc   = (const float*)d_in[2];
    const float* motion_loc  = (const float*)d_in[3];
    const int*   label       = (const int*)d_in[4];
    const float* Wp          = (const float*)d_in[5];
    const float* bp          = (const float*)d_in[6];
    const float* Wc          = (const float*)d_in[7];
    const float* bc          = (const float*)d_in[8];
    float* out = (float*)d_out;

    char* ws = (char*)d_ws;
    int* idx_buf = (int*)ws;                                           // 96 KB
    float* xpart = (float*)(ws + (128 << 10));                         // 2 MB
    float* hpart = (float*)(ws + (128 << 10) + (2 << 20));             // 8 MB
    float* lpart = (float*)(ws + (128 << 10) + (10 << 20));            // 0.2 MB

    knn_idx_kernel<<<BB_ * 8, 256, 0, stream>>>(scene_loc, motion_loc, idx_buf);
    fuse_mean_kernel<<<BB_ * 16, 256, 0, stream>>>(scene_feat, motion_feat, idx_buf, xpart);
    fc1_kernel<<<256, 256, 0, stream>>>(xpart, Wp, hpart);
    fc2_partial_kernel<<<256, 256, 0, stream>>>(hpart, bp, Wc, lpart);
    logits_loss_kernel<<<1, 256, 0, stream>>>(lpart, bc, label, out);
}

// Round 4
// 126.207 us; speedup vs baseline: 1.7345x; 1.0456x over previous
//
#include <hip/hip_runtime.h>
#include <hip/hip_bf16.h>
#include <math.h>

#define BB_ 32
#define NM_ 256
#define NO_ 1024
#define DD_ 1024
#define HID_ 2048
#define CC_ 200
#define KK_ 3
#define EPS_ 0.001f
#define ALPHA_ 0.3f
#define NSEG_ 32

// ---------------- Kernel 1: top-3 nearest scene indices per motion token ---------
// grid = B*8 blocks, 256 threads. 8 threads per motion token, 32 tokens/block.
__device__ __forceinline__ bool lex_less(float nd, int ni, float d, int i) {
    return (nd < d) || (nd == d && ni < i);
}

__device__ __forceinline__ void ins3(float nd, int ni,
                                     float& d0, int& i0, float& d1, int& i1,
                                     float& d2, int& i2) {
    if (lex_less(nd, ni, d1, i1)) {
        d2 = d1; i2 = i1;
        if (lex_less(nd, ni, d0, i0)) { d1 = d0; i1 = i0; d0 = nd; i0 = ni; }
        else { d1 = nd; i1 = ni; }
    } else if (lex_less(nd, ni, d2, i2)) {
        d2 = nd; i2 = ni;
    }
}

__global__ __launch_bounds__(256) void knn_idx_kernel(
        const float* __restrict__ scene_loc, const float* __restrict__ motion_loc,
        int* __restrict__ idx_buf) {
    int bx = blockIdx.x;
    int b = bx >> 3;
    int mc = bx & 7;
    __shared__ float2 sloc[NO_];
    const float2* sl = (const float2*)(scene_loc + (size_t)b * NO_ * 2);
    for (int i = threadIdx.x; i < NO_; i += 256) sloc[i] = sl[i];
    __syncthreads();

    int m = mc * 32 + (threadIdx.x >> 3);
    int lane8 = threadIdx.x & 7;
    float2 ml = ((const float2*)(motion_loc + (size_t)b * NM_ * 2))[m];

    float d0 = INFINITY, d1 = INFINITY, d2 = INFINITY;
    int i0 = NO_, i1 = NO_, i2 = NO_;
    for (int o = lane8; o < NO_; o += 8) {
        float dx = ml.x - sloc[o].x;
        float dy = ml.y - sloc[o].y;
        // match reference per-op rounding (no fma contraction), then sqrt
        float dist = __fsqrt_rn(__fadd_rn(__fmul_rn(dx, dx), __fmul_rn(dy, dy)));
        ins3(dist, o, d0, i0, d1, i1, d2, i2);
    }
    for (int mask = 1; mask <= 4; mask <<= 1) {
        float e0 = __shfl_xor(d0, mask); int j0 = __shfl_xor(i0, mask);
        float e1 = __shfl_xor(d1, mask); int j1 = __shfl_xor(i1, mask);
        float e2 = __shfl_xor(d2, mask); int j2 = __shfl_xor(i2, mask);
        ins3(e0, j0, d0, i0, d1, i1, d2, i2);
        ins3(e1, j1, d0, i0, d1, i1, d2, i2);
        ins3(e2, j2, d0, i0, d1, i1, d2, i2);
    }
    if (lane8 == 0) {
        int base = (b * NM_ + m) * 3;
        idx_buf[base]     = i0;
        idx_buf[base + 1] = i1;
        idx_buf[base + 2] = i2;
    }
}

// ---------------- Kernel 2: per-batch scene counts (once per b) -------------------
__global__ __launch_bounds__(256) void count_kernel(
        const int* __restrict__ idx_buf, int* __restrict__ counts) {
    int b = blockIdx.x;
    int t = threadIdx.x;
    __shared__ int cnt[NO_];
    for (int i = t; i < NO_; i += 256) cnt[i] = 0;
    __syncthreads();
    for (int i = t; i < NM_ * KK_; i += 256)
        atomicAdd(&cnt[idx_buf[b * NM_ * KK_ + i]], 1);
    __syncthreads();
    for (int i = t; i < NO_; i += 256) counts[b * NO_ + i] = cnt[i];
}

// ---------------- Kernel 3: x[b,d] partial sums ----------------------------------
// grid = B*32 blocks; block (b,s) handles motion rows r≡s (mod 32) and scene rows
// o≡s (mod 32), compacted via wave ballot (deterministic, o-ascending).
__global__ __launch_bounds__(256) void fuse_mean_kernel(
        const float* __restrict__ scene_feat, const float* __restrict__ motion_feat,
        const int* __restrict__ counts, float* __restrict__ xpart) {
    int bx = blockIdx.x;
    int b = bx >> 5;
    int s = bx & 31;
    int t = threadIdx.x;
    const float wmot = 1.0f / (float)NM_;
    const float wsc = ALPHA_ / (float)(NM_ * KK_);

    __shared__ float wls[32];
    __shared__ int ols[32];
    __shared__ int msh;
    if (t < 32) {
        int o = s + (t << 5);
        int c = counts[b * NO_ + o];
        unsigned long long ball = __ballot(c != 0);
        int pos = __popcll(ball & ((1ull << t) - 1ull));
        if (c != 0) { wls[pos] = wsc * (float)c; ols[pos] = o; }
        if (t == 0) msh = __popcll(ball);
    }
    __syncthreads();
    int m = msh;

    float4 acc = make_float4(0.f, 0.f, 0.f, 0.f);
    // motion rows: r = s + 32j, j = 0..7 — 8 independent loads
    const float4* mf = (const float4*)(motion_feat + (size_t)b * NM_ * DD_);
    #pragma unroll
    for (int j = 0; j < 8; ++j) {
        float4 v = mf[(size_t)(s + (j << 5)) * 256 + t];
        acc.x = fmaf(wmot, v.x, acc.x);
        acc.y = fmaf(wmot, v.y, acc.y);
        acc.z = fmaf(wmot, v.z, acc.z);
        acc.w = fmaf(wmot, v.w, acc.w);
    }
    // compacted scene rows
    const float4* sf = (const float4*)(scene_feat + (size_t)b * NO_ * DD_);
    #pragma unroll 4
    for (int i = 0; i < m; ++i) {
        float w = wls[i];
        float4 v = sf[(size_t)ols[i] * 256 + t];
        acc.x = fmaf(w, v.x, acc.x);
        acc.y = fmaf(w, v.y, acc.y);
        acc.z = fmaf(w, v.z, acc.z);
        acc.w = fmaf(w, v.w, acc.w);
    }
    ((float4*)(xpart + ((size_t)s * BB_ + b) * DD_))[t] = acc;
}

// ---------------- Kernel 4: x = sum over segments --------------------------------
// grid = B blocks, 256 threads (1 float4 per thread).
__global__ __launch_bounds__(256) void xsum_kernel(
        const float* __restrict__ xpart, float* __restrict__ x) {
    int b = blockIdx.x;
    int t = threadIdx.x;
    float4 acc = make_float4(0.f, 0.f, 0.f, 0.f);
    #pragma unroll 8
    for (int s = 0; s < NSEG_; ++s) {
        float4 v = ((const float4*)(xpart + ((size_t)s * BB_ + b) * DD_))[t];
        acc.x += v.x; acc.y += v.y; acc.z += v.z; acc.w += v.w;
    }
    ((float4*)(x + (size_t)b * DD_))[t] = acc;
}

// ---------------- Kernel 5: hpre partials = x @ Wp -------------------------------
// grid = 32 dchunks * 8 jchunks = 256 blocks, 256 threads. acc[32] (all batches).
__global__ __launch_bounds__(256) void fc1_kernel(
        const float* __restrict__ x, const float* __restrict__ Wp,
        float* __restrict__ hpart) {
    int jc = blockIdx.x & 7;
    int dc = blockIdx.x >> 3;
    int t = threadIdx.x;
    int j = jc * 256 + t;

    __shared__ float xs[BB_ * 32];
    for (int idx = t; idx < BB_ * 32; idx += 256) {
        int bb = idx >> 5;
        int dl = idx & 31;
        xs[idx] = x[(size_t)bb * DD_ + dc * 32 + dl];
    }
    __syncthreads();

    float acc[BB_];
    #pragma unroll
    for (int bb = 0; bb < BB_; ++bb) acc[bb] = 0.f;

    int d0 = dc * 32;
    for (int dl = 0; dl < 32; ++dl) {
        float w = Wp[(size_t)(d0 + dl) * HID_ + j];
        #pragma unroll
        for (int bb = 0; bb < BB_; ++bb)
            acc[bb] = fmaf(xs[bb * 32 + dl], w, acc[bb]);
    }
    #pragma unroll
    for (int bb = 0; bb < BB_; ++bb)
        hpart[((size_t)dc * BB_ + bb) * HID_ + j] = acc[bb];
}

// ---------------- Kernel 6: lpart[kc][b][c] = sum_k gelu(h)[b,k]*Wc[k,c] ---------
// grid = 8 kchunks * 32 b = 256 blocks, 256 threads.
__global__ __launch_bounds__(256) void fc2_partial_kernel(
        const float* __restrict__ hpart, const float* __restrict__ bp,
        const float* __restrict__ Wc, float* __restrict__ lpart) {
    int bx = blockIdx.x;
    int b = bx & 31;
    int kc = bx >> 5;
    int t = threadIdx.x;
    __shared__ float hs[256];

    int k = kc * 256 + t;
    float sum = bp[k];
    #pragma unroll
    for (int dcc = 0; dcc < 32; ++dcc)
        sum += hpart[((size_t)dcc * BB_ + b) * HID_ + k];
    // exact GELU
    hs[t] = 0.5f * sum * (1.0f + erff(sum * 0.70710678118654752f));
    __syncthreads();

    if (t < CC_) {
        float acc0 = 0.f, acc1 = 0.f;
        const float* wc = Wc + (size_t)kc * 256 * CC_ + t;
        #pragma unroll 8
        for (int k2 = 0; k2 < 256; k2 += 2) {
            acc0 = fmaf(hs[k2],     wc[(size_t)k2 * CC_],       acc0);
            acc1 = fmaf(hs[k2 + 1], wc[(size_t)(k2 + 1) * CC_], acc1);
        }
        lpart[((size_t)kc * BB_ + b) * CC_ + t] = acc0 + acc1;
    }
}

// ---------------- Kernel 7: logits = sum_kc lpart + bc; then smoothed CE loss -----
__global__ __launch_bounds__(256) void logits_loss_kernel(
        const float* __restrict__ lpart, const float* __restrict__ bc,
        const int* __restrict__ label, float* __restrict__ out) {
    int t = threadIdx.x;
    __shared__ float slog[BB_ * CC_];
    __shared__ float lossb[BB_];

    for (int idx = t; idx < BB_ * CC_; idx += 256) {
        int b = idx / CC_;
        int c = idx - b * CC_;
        float acc = bc[c];
        #pragma unroll
        for (int kc = 0; kc < 8; ++kc)
            acc += lpart[((size_t)kc * BB_ + b) * CC_ + c];
        slog[idx] = acc;
        out[idx] = acc;
    }
    __syncthreads();

    int b = t >> 3;
    int lane = t & 7;
    float v[25];
    float m = -INFINITY, ssum = 0.f;
    #pragma unroll
    for (int i = 0; i < 25; ++i) {
        float x = slog[b * CC_ + lane + i * 8];
        v[i] = x;
        m = fmaxf(m, x);
        ssum += x;
    }
    for (int mask = 1; mask < 8; mask <<= 1) m = fmaxf(m, __shfl_xor(m, mask));
    for (int mask = 1; mask < 8; mask <<= 1) ssum += __shfl_xor(ssum, mask);
    float e = 0.f;
    #pragma unroll
    for (int i = 0; i < 25; ++i) e += expf(v[i] - m);
    for (int mask = 1; mask < 8; mask <<= 1) e += __shfl_xor(e, mask);
    float logZ = m + logf(e);

    if (lane == 0) {
        float nll = logZ - slog[b * CC_ + label[b]];
        float smooth = logZ - ssum * (1.0f / (float)CC_);
        lossb[b] = (1.0f - EPS_) * nll + EPS_ * smooth;
    }
    __syncthreads();
    if (t == 0) {
        float s = 0.f;
        for (int i = 0; i < BB_; ++i) s += lossb[i];
        out[BB_ * CC_] = s * (1.0f / (float)BB_);
    }
}

extern "C" void kernel_launch(void* const* d_in, const int* in_sizes, int n_in,
                              void* d_out, int out_size, void* d_ws, size_t ws_size,
                              hipStream_t stream) {
    const float* scene_feat  = (const float*)d_in[0];
    const float* motion_feat = (const float*)d_in[1];
    const float* scene_loc   = (const float*)d_in[2];
    const float* motion_loc  = (const float*)d_in[3];
    const int*   label       = (const int*)d_in[4];
    const float* Wp          = (const float*)d_in[5];
    const float* bp          = (const float*)d_in[6];
    const float* Wc          = (const float*)d_in[7];
    const float* bc          = (const float*)d_in[8];
    float* out = (float*)d_out;

    char* ws = (char*)d_ws;
    int*   idx_buf = (int*)ws;                              // 96 KB
    int*   counts  = (int*)(ws + (128 << 10));              // 128 KB
    float* xpart   = (float*)(ws + (256 << 10));            // 4 MB  [32][32][1024]
    float* x       = (float*)(ws + (8 << 20));              // 128 KB
    float* hpart   = (float*)(ws + (16 << 20));             // 8 MB  [32][32][2048]
    float* lpart   = (float*)(ws + (32 << 20));             // 200 KB

    knn_idx_kernel<<<BB_ * 8, 256, 0, stream>>>(scene_loc, motion_loc, idx_buf);
    count_kernel<<<BB_, 256, 0, stream>>>(idx_buf, counts);
    fuse_mean_kernel<<<BB_ * NSEG_, 256, 0, stream>>>(scene_feat, motion_feat, counts, xpart);
    xsum_kernel<<<BB_, 256, 0, stream>>>(xpart, x);
    fc1_kernel<<<256, 256, 0, stream>>>(x, Wp, hpart);
    fc2_partial_kernel<<<256, 256, 0, stream>>>(hpart, bp, Wc, lpart);
    logits_loss_kernel<<<1, 256, 0, stream>>>(lpart, bc, label, out);
}

// Round 5
// 125.945 us; speedup vs baseline: 1.7381x; 1.0021x over previous
//
#include <hip/hip_runtime.h>
#include <hip/hip_bf16.h>
#include <math.h>

#define BB_ 32
#define NM_ 256
#define NO_ 1024
#define DD_ 1024
#define HID_ 2048
#define CC_ 200
#define KK_ 3
#define EPS_ 0.001f
#define ALPHA_ 0.3f
#define NSEG_ 32

// ---------------- Kernel 1: top-3 nearest scene indices per motion token ---------
// grid = B*8 blocks, 256 threads. 8 threads per motion token, 32 tokens/block.
__device__ __forceinline__ bool lex_less(float nd, int ni, float d, int i) {
    return (nd < d) || (nd == d && ni < i);
}

__device__ __forceinline__ void ins3(float nd, int ni,
                                     float& d0, int& i0, float& d1, int& i1,
                                     float& d2, int& i2) {
    if (lex_less(nd, ni, d1, i1)) {
        d2 = d1; i2 = i1;
        if (lex_less(nd, ni, d0, i0)) { d1 = d0; i1 = i0; d0 = nd; i0 = ni; }
        else { d1 = nd; i1 = ni; }
    } else if (lex_less(nd, ni, d2, i2)) {
        d2 = nd; i2 = ni;
    }
}

__global__ __launch_bounds__(256) void knn_idx_kernel(
        const float* __restrict__ scene_loc, const float* __restrict__ motion_loc,
        int* __restrict__ idx_buf) {
    int bx = blockIdx.x;
    int b = bx >> 3;
    int mc = bx & 7;
    __shared__ float2 sloc[NO_];
    const float2* sl = (const float2*)(scene_loc + (size_t)b * NO_ * 2);
    for (int i = threadIdx.x; i < NO_; i += 256) sloc[i] = sl[i];
    __syncthreads();

    int m = mc * 32 + (threadIdx.x >> 3);
    int lane8 = threadIdx.x & 7;
    float2 ml = ((const float2*)(motion_loc + (size_t)b * NM_ * 2))[m];

    float d0 = INFINITY, d1 = INFINITY, d2 = INFINITY;
    int i0 = NO_, i1 = NO_, i2 = NO_;
    for (int o = lane8; o < NO_; o += 8) {
        float dx = ml.x - sloc[o].x;
        float dy = ml.y - sloc[o].y;
        // match reference per-op rounding (no fma contraction), then sqrt
        float dist = __fsqrt_rn(__fadd_rn(__fmul_rn(dx, dx), __fmul_rn(dy, dy)));
        ins3(dist, o, d0, i0, d1, i1, d2, i2);
    }
    for (int mask = 1; mask <= 4; mask <<= 1) {
        float e0 = __shfl_xor(d0, mask); int j0 = __shfl_xor(i0, mask);
        float e1 = __shfl_xor(d1, mask); int j1 = __shfl_xor(i1, mask);
        float e2 = __shfl_xor(d2, mask); int j2 = __shfl_xor(i2, mask);
        ins3(e0, j0, d0, i0, d1, i1, d2, i2);
        ins3(e1, j1, d0, i0, d1, i1, d2, i2);
        ins3(e2, j2, d0, i0, d1, i1, d2, i2);
    }
    if (lane8 == 0) {
        int base = (b * NM_ + m) * 3;
        idx_buf[base]     = i0;
        idx_buf[base + 1] = i1;
        idx_buf[base + 2] = i2;
    }
}

// ---------------- Kernel 2: x[b,d] partial sums (inline counting) -----------------
// grid = B*32 blocks; block (b,s): builds per-b counts in LDS from idx_buf, then
// handles motion rows r≡s (mod 32) and scene rows o≡s (mod 32), compacted via
// wave ballot (deterministic, o-ascending).
__global__ __launch_bounds__(256) void fuse_mean_kernel(
        const float* __restrict__ scene_feat, const float* __restrict__ motion_feat,
        const int* __restrict__ idx_buf, float* __restrict__ xpart) {
    int bx = blockIdx.x;
    int b = bx >> 5;
    int s = bx & 31;
    int t = threadIdx.x;
    const float wmot = 1.0f / (float)NM_;
    const float wsc = ALPHA_ / (float)(NM_ * KK_);

    __shared__ int cnt[NO_];
    __shared__ float wls[32];
    __shared__ int ols[32];
    __shared__ int msh;
    for (int i = t; i < NO_; i += 256) cnt[i] = 0;
    __syncthreads();
    const int* ib = idx_buf + b * NM_ * KK_;
    for (int i = t; i < NM_ * KK_; i += 256)
        atomicAdd(&cnt[ib[i]], 1);
    __syncthreads();

    if (t < 32) {
        int o = s + (t << 5);
        int c = cnt[o];
        unsigned long long ball = __ballot(c != 0);
        int pos = __popcll(ball & ((1ull << t) - 1ull));
        if (c != 0) { wls[pos] = wsc * (float)c; ols[pos] = o; }
        if (t == 0) msh = __popcll(ball);
    }
    __syncthreads();
    int m = msh;

    float4 acc = make_float4(0.f, 0.f, 0.f, 0.f);
    // motion rows: r = s + 32j, j = 0..7 — 8 independent loads
    const float4* mf = (const float4*)(motion_feat + (size_t)b * NM_ * DD_);
    #pragma unroll
    for (int j = 0; j < 8; ++j) {
        float4 v = mf[(size_t)(s + (j << 5)) * 256 + t];
        acc.x = fmaf(wmot, v.x, acc.x);
        acc.y = fmaf(wmot, v.y, acc.y);
        acc.z = fmaf(wmot, v.z, acc.z);
        acc.w = fmaf(wmot, v.w, acc.w);
    }
    // compacted scene rows
    const float4* sf = (const float4*)(scene_feat + (size_t)b * NO_ * DD_);
    #pragma unroll 4
    for (int i = 0; i < m; ++i) {
        float w = wls[i];
        float4 v = sf[(size_t)ols[i] * 256 + t];
        acc.x = fmaf(w, v.x, acc.x);
        acc.y = fmaf(w, v.y, acc.y);
        acc.z = fmaf(w, v.z, acc.z);
        acc.w = fmaf(w, v.w, acc.w);
    }
    ((float4*)(xpart + ((size_t)s * BB_ + b) * DD_))[t] = acc;
}

// ---------------- Kernel 3: hpre partials = x @ Wp (inline xpart reduction) -------
// grid = 32 dchunks * 8 jchunks = 256 blocks, 256 threads. acc[32] (all batches).
// xs[bb][dl] = sum_s xpart[s][bb][dc*32+dl]  (s ascending — bit-identical to xsum)
__global__ __launch_bounds__(256) void fc1_kernel(
        const float* __restrict__ xpart, const float* __restrict__ Wp,
        float* __restrict__ hpart) {
    int jc = blockIdx.x & 7;
    int dc = blockIdx.x >> 3;
    int t = threadIdx.x;
    int j = jc * 256 + t;

    __shared__ float xs[BB_ * 32];
    for (int idx = t; idx < BB_ * 32; idx += 256) {
        int bb = idx >> 5;
        int dl = idx & 31;
        float sum = 0.f;
        #pragma unroll 8
        for (int s = 0; s < NSEG_; ++s)
            sum += xpart[((size_t)s * BB_ + bb) * DD_ + dc * 32 + dl];
        xs[idx] = sum;
    }
    __syncthreads();

    float acc[BB_];
    #pragma unroll
    for (int bb = 0; bb < BB_; ++bb) acc[bb] = 0.f;

    int d0 = dc * 32;
    for (int dl = 0; dl < 32; ++dl) {
        float w = Wp[(size_t)(d0 + dl) * HID_ + j];
        #pragma unroll
        for (int bb = 0; bb < BB_; ++bb)
            acc[bb] = fmaf(xs[bb * 32 + dl], w, acc[bb]);
    }
    #pragma unroll
    for (int bb = 0; bb < BB_; ++bb)
        hpart[((size_t)dc * BB_ + bb) * HID_ + j] = acc[bb];
}

// ---------------- Kernel 4: lpart[kc][b][c] = sum_k gelu(h)[b,k]*Wc[k,c] ---------
// grid = 8 kchunks * 32 b = 256 blocks, 256 threads.
__global__ __launch_bounds__(256) void fc2_partial_kernel(
        const float* __restrict__ hpart, const float* __restrict__ bp,
        const float* __restrict__ Wc, float* __restrict__ lpart) {
    int bx = blockIdx.x;
    int b = bx & 31;
    int kc = bx >> 5;
    int t = threadIdx.x;
    __shared__ float hs[256];

    int k = kc * 256 + t;
    float sum = bp[k];
    #pragma unroll
    for (int dcc = 0; dcc < 32; ++dcc)
        sum += hpart[((size_t)dcc * BB_ + b) * HID_ + k];
    // exact GELU
    hs[t] = 0.5f * sum * (1.0f + erff(sum * 0.70710678118654752f));
    __syncthreads();

    if (t < CC_) {
        float acc0 = 0.f, acc1 = 0.f;
        const float* wc = Wc + (size_t)kc * 256 * CC_ + t;
        #pragma unroll 8
        for (int k2 = 0; k2 < 256; k2 += 2) {
            acc0 = fmaf(hs[k2],     wc[(size_t)k2 * CC_],       acc0);
            acc1 = fmaf(hs[k2 + 1], wc[(size_t)(k2 + 1) * CC_], acc1);
        }
        lpart[((size_t)kc * BB_ + b) * CC_ + t] = acc0 + acc1;
    }
}

// ---------------- Kernel 5: logits = sum_kc lpart + bc; then smoothed CE loss -----
__global__ __launch_bounds__(256) void logits_loss_kernel(
        const float* __restrict__ lpart, const float* __restrict__ bc,
        const int* __restrict__ label, float* __restrict__ out) {
    int t = threadIdx.x;
    __shared__ float slog[BB_ * CC_];
    __shared__ float lossb[BB_];

    for (int idx = t; idx < BB_ * CC_; idx += 256) {
        int b = idx / CC_;
        int c = idx - b * CC_;
        float acc = bc[c];
        #pragma unroll
        for (int kc = 0; kc < 8; ++kc)
            acc += lpart[((size_t)kc * BB_ + b) * CC_ + c];
        slog[idx] = acc;
        out[idx] = acc;
    }
    __syncthreads();

    int b = t >> 3;
    int lane = t & 7;
    float v[25];
    float m = -INFINITY, ssum = 0.f;
    #pragma unroll
    for (int i = 0; i < 25; ++i) {
        float x = slog[b * CC_ + lane + i * 8];
        v[i] = x;
        m = fmaxf(m, x);
        ssum += x;
    }
    for (int mask = 1; mask < 8; mask <<= 1) m = fmaxf(m, __shfl_xor(m, mask));
    for (int mask = 1; mask < 8; mask <<= 1) ssum += __shfl_xor(ssum, mask);
    float e = 0.f;
    #pragma unroll
    for (int i = 0; i < 25; ++i) e += expf(v[i] - m);
    for (int mask = 1; mask < 8; mask <<= 1) e += __shfl_xor(e, mask);
    float logZ = m + logf(e);

    if (lane == 0) {
        float nll = logZ - slog[b * CC_ + label[b]];
        float smooth = logZ - ssum * (1.0f / (float)CC_);
        lossb[b] = (1.0f - EPS_) * nll + EPS_ * smooth;
    }
    __syncthreads();
    if (t == 0) {
        float s = 0.f;
        for (int i = 0; i < BB_; ++i) s += lossb[i];
        out[BB_ * CC_] = s * (1.0f / (float)BB_);
    }
}

extern "C" void kernel_launch(void* const* d_in, const int* in_sizes, int n_in,
                              void* d_out, int out_size, void* d_ws, size_t ws_size,
                              hipStream_t stream) {
    const float* scene_feat  = (const float*)d_in[0];
    const float* motion_feat = (const float*)d_in[1];
    const float* scene_loc   = (const float*)d_in[2];
    const float* motion_loc  = (const float*)d_in[3];
    const int*   label       = (const int*)d_in[4];
    const float* Wp          = (const float*)d_in[5];
    const float* bp          = (const float*)d_in[6];
    const float* Wc          = (const float*)d_in[7];
    const float* bc          = (const float*)d_in[8];
    float* out = (float*)d_out;

    char* ws = (char*)d_ws;
    int*   idx_buf = (int*)ws;                              // 96 KB
    float* xpart   = (float*)(ws + (256 << 10));            // 4 MB  [32][32][1024]
    float* hpart   = (float*)(ws + (16 << 20));             // 8 MB  [32][32][2048]
    float* lpart   = (float*)(ws + (32 << 20));             // 200 KB

    knn_idx_kernel<<<BB_ * 8, 256, 0, stream>>>(scene_loc, motion_loc, idx_buf);
    fuse_mean_kernel<<<BB_ * NSEG_, 256, 0, stream>>>(scene_feat, motion_feat, idx_buf, xpart);
    fc1_kernel<<<256, 256, 0, stream>>>(xpart, Wp, hpart);
    fc2_partial_kernel<<<256, 256, 0, stream>>>(hpart, bp, Wc, lpart);
    logits_loss_kernel<<<1, 256, 0, stream>>>(lpart, bc, label, out);
}